// Round 4
// baseline (178.891 us; speedup 1.0000x reference)
//
#include <hip/hip_runtime.h>

#define PLANE 65536
#define WIDTH 256
#define PADW 258
#define PADPLANE 66564   // 258*258

typedef __bf16 v8bf __attribute__((ext_vector_type(8)));
typedef float  v4f  __attribute__((ext_vector_type(4)));

typedef const __attribute__((address_space(1))) unsigned int* gas_ptr;
typedef __attribute__((address_space(3))) unsigned int* las_ptr;

// async global->LDS, 16 B per lane; LDS dest = wave-uniform base + lane*16
__device__ __forceinline__ void gl_lds(const void* g, void* l) {
  __builtin_amdgcn_global_load_lds((gas_ptr)g, (las_ptr)l, 16, 0, 0);
}

// self-inverse 16B-chunk swizzle within 8-chunk groups; ~0 conflicts measured
__device__ __forceinline__ int swz(int c) {
  return (c & ~7) | ((c & 7) ^ ((c >> 3) & 7));
}

__device__ __forceinline__ int m6(int x) { return x >= 6 ? x - 6 : x; }

__device__ __forceinline__ unsigned int pack2(float a, float b) {
  __bf16 ba = (__bf16)a, bb = (__bf16)b;
  unsigned short sa = __builtin_bit_cast(unsigned short, ba);
  unsigned short sb = __builtin_bit_cast(unsigned short, bb);
  return (unsigned int)sa | ((unsigned int)sb << 16);
}

// ---------------------------------------------------------------------------
// wz_k: fused weight-prep + padding-ring zeroing (act1 + act3 only; act2 is
// now LDS-resident in the fused conv23 kernel).
// ---------------------------------------------------------------------------
#define WT_N 37440                       // 288+18432+18432+288
#define ZR_N (8 * 1028 * 32)             // 16+16 uints per ring px
__global__ __launch_bounds__(256) void wz_k(
    const float* __restrict__ w1, const float* __restrict__ w2,
    const float* __restrict__ w3, const float* __restrict__ w4,
    float* __restrict__ w1t, __bf16* __restrict__ B2t,
    __bf16* __restrict__ B3t, float* __restrict__ w4t,
    __bf16* __restrict__ a1, __bf16* __restrict__ a3)
{
  int t = blockIdx.x * 256 + threadIdx.x;
  if (t < WT_N) {
    if (t < 288) {                       // w1: [32][1][9] -> [tap][32]
      int tap = t >> 5, cout = t & 31;
      w1t[t] = w1[cout * 9 + tap];
    }
    int t2 = t - 288;
    if (t2 >= 0 && t2 < 18432) {         // 64 x 288
      int cout = t2 / 288, k = t2 % 288;
      int tap = k / 32, cin = k % 32;
      B2t[t2] = (__bf16)w2[cout * 288 + cin * 9 + tap];
    }
    int t3 = t - (288 + 18432);
    if (t3 >= 0 && t3 < 18432) {         // 32 x 576
      int cout = t3 / 576, k = t3 % 576;
      int tap = k / 64, cin = k % 64;
      B3t[t3] = (__bf16)w3[cout * 576 + cin * 9 + tap];
    }
    int t4 = t - (288 + 18432 + 18432);
    if (t4 >= 0 && t4 < 288) {           // w4: [1][32][9] -> [tap][32]
      int tap = t4 >> 5, cin = t4 & 31;
      w4t[t4] = w4[cin * 9 + tap];
    }
    return;
  }
  int idx = t - WT_N;
  if (idx >= ZR_N) return;
  unsigned int* p;
  const int R1 = 8 * 1028 * 16;
  if (idx < R1) p = (unsigned int*)a1;
  else         { p = (unsigned int*)a3; idx -= R1; }
  int ch = idx & 15;
  int pr = idx >> 4;                 // 0 .. 8*1028-1
  int b = pr / 1028, r = pr % 1028;
  int y, x;
  if      (r < 258) { y = 0;           x = r; }
  else if (r < 516) { y = 257;         x = r - 258; }
  else if (r < 772) { y = r - 516 + 1; x = 0; }
  else              { y = r - 772 + 1; x = 257; }
  p[((size_t)b * PADPLANE + y * PADW + x) * 16 + ch] = 0;
}

// ---------------------------------------------------------------------------
// prepconv1_k: fused prep + conv1 (unchanged).
// ---------------------------------------------------------------------------
__global__ __launch_bounds__(256) void prepconv1_k(
    const float* __restrict__ inputs, const float* __restrict__ H0,
    const float* __restrict__ C0, const float* __restrict__ c2p,
    const float* __restrict__ sfp, const float* __restrict__ w1t,
    const float* __restrict__ b1, float* __restrict__ dout,
    __bf16* __restrict__ act1)
{
  const int x = threadIdx.x, y = blockIdx.x, b = blockIdx.y;
  const int p = b * PLANE + y * WIDTH + x;
  const float c2 = c2p[0], sf = sfp[0], rsf = 1.0f / sf;

  float iv[3][3], hv[3][3];
  #pragma unroll
  for (int dy = 0; dy < 3; dy++) {
    int yy = y + dy - 1;
    #pragma unroll
    for (int dx = 0; dx < 3; dx++) {
      int xx = x + dx - 1;
      bool ok = (yy >= 0 && yy < 256 && xx >= 0 && xx < 256);
      int pn = p + (dy - 1) * WIDTH + (dx - 1);
      iv[dy][dx] = ok ? inputs[pn] : 0.f;
      hv[dy][dx] = ok ? H0[pn]     : 0.f;
    }
  }
  const float in = iv[1][1], h0 = hv[1][1];
  const float c0a = C0[b * 131072 + y * WIDTH + x];
  float lap = iv[0][1] + iv[2][1] + iv[1][0] + iv[1][2] - 4.f * in;
  float Hv = 2.f * in - c0a + c2 * lap;
  float V  = in - h0;
  dout[524288 + p]  = Hv;                               // H
  dout[2097152 + p] = V;                                // V
  dout[1048576 + b * 131072 + y * WIDTH + x]         = in;   // C_new[:,0]
  dout[1048576 + b * 131072 + 65536 + y * WIDTH + x] = c0a;  // C_new[:,1]

  float acc[32];
  #pragma unroll
  for (int i = 0; i < 32; i++) acc[i] = b1[i];
  #pragma unroll
  for (int tap = 0; tap < 9; tap++) {
    float v = (iv[tap / 3][tap % 3] - hv[tap / 3][tap % 3]) * rsf;
    const float* wp = w1t + tap * 32;                   // uniform
    #pragma unroll
    for (int i = 0; i < 32; i++) acc[i] = fmaf(wp[i], v, acc[i]);
  }
  unsigned int u[16];
  #pragma unroll
  for (int j = 0; j < 16; j++)
    u[j] = pack2(fmaxf(acc[2*j], 0.f), fmaxf(acc[2*j+1], 0.f));
  size_t pa = ((size_t)b * PADPLANE + (y+1) * PADW + (x+1)) * 32;
  uint4* op = reinterpret_cast<uint4*>(act1 + pa);
  #pragma unroll
  for (int j = 0; j < 4; j++)
    op[j] = make_uint4(u[4*j], u[4*j+1], u[4*j+2], u[4*j+3]);
}

// ---------------------------------------------------------------------------
// conv23_k: FUSED conv2 (32->64) + conv3 (64->32). act2 never touches HBM
// (saves ~153 MB of the pipeline's ~310 MB traffic).
//
// Block = 4 waves, output tile = 64 px (x) * 8 rows of act3.
// act2 ring: 6 slots x (66 px * 64 ch bf16)   — slot i <-> real x0-1+i.
// act1 ring: 6 slots x (68 px * 32 ch bf16)   — slot j <-> padded x0-1+j,
//            staged via gl_lds, rows clamped at plane edges.
// PRODUCE (conv2): waves split 64 couts (16 each, breg2 9 frags, nt=1);
//   5 M-tiles cover 80 px (ragged tail masked); acc -> ReLU bf16 -> swizzled
//   ds_write_b16 into act2 ring. Halo slots (x edges / y zero-rows) zeroed
//   explicitly, reproducing the old global pad-ring semantics.
// CONSUME (conv3): identical arithmetic/order to prior conv3_k, but waves
//   remapped to (px-half Mh, cout-half ntw) so breg3 = 9x2 frags (72 VGPR,
//   not 144) — keeps total VGPR ~200 (r1 spill lesson).
// Schedule per pair-step ps: stage act1 k=2ps+6,7 (async) -> produce rows
//   2ps+2,3 -> lgkmcnt(0)+barrier -> consume pair ps -> vmcnt(16)+barrier
//   (16 = this iter's epilogue stores; the 4 older stage ops must land).
// ---------------------------------------------------------------------------
#define A1ROWB 4352   // 68 px * 32 ch * 2 B = 272 chunks
#define A2ROWB 8448   // 66 px * 64 ch * 2 B = 528 chunks
__global__ __launch_bounds__(256, 2) void conv23_k(
    const __bf16* __restrict__ act1, const __bf16* __restrict__ B2t,
    const float* __restrict__ b2, const __bf16* __restrict__ B3t,
    const float* __restrict__ b3, __bf16* __restrict__ act3)
{
  const int lane = threadIdx.x & 63, wave = threadIdx.x >> 6;
  const int l15 = lane & 15, q = lane >> 4;
  const int y0 = blockIdx.x * 8, xt = blockIdx.y, b = blockIdx.z;
  const int x0 = xt * 64;
  __shared__ __align__(16) char smem[6 * A2ROWB + 6 * A1ROWB + 1024];
  char* a2r = smem;                       // act2 ring
  char* a1r = smem + 6 * A2ROWB;          // act1 ring (+1KB pad for ragged
                                          //  M-tile over-reads)
  const __bf16* plane = act1 + (size_t)b * PADPLANE * 32;

  // stage act1 rel row k (padded row y0-1+k, clamped) into ring slot
  auto stageA1 = [&](int k, int slot) {
    int a = y0 - 1 + k;
    a = a < 0 ? 0 : (a > 257 ? 257 : a);
    // padded x from x0-1: for x0==0 reads 64B before the row (valid ws
    // memory, value lands in slot j=0 which only feeds the x-halo act2
    // slot that gets explicitly zeroed).
    const char* g = (const char*)(plane + ((size_t)a * PADW + x0 - 1) * 32);
    char* lrow = a1r + slot * A1ROWB;
    const int base = wave * 68;
    gl_lds(g + (size_t)swz(base + lane) * 16, lrow + base * 16);
    if (lane < 4)
      gl_lds(g + (size_t)swz(base + 64 + lane) * 16, lrow + (base + 64) * 16);
  };

  // conv2 weights: this wave's 16 couts
  v8bf breg2[9];
  #pragma unroll
  for (int tap = 0; tap < 9; tap++)
    breg2[tap] = *(const v8bf*)(B2t + (size_t)(wave * 16 + l15) * 288
                                    + tap * 32 + q * 8);
  const float bv2 = b2[wave * 16 + l15];

  // conv3 weights: wave = (Mh = wave>>1 px-half, ntw = wave&1 cout-half)
  const int Mh = wave >> 1, ntw = wave & 1;
  v8bf breg3[9][2];
  #pragma unroll
  for (int tap = 0; tap < 9; tap++)
    #pragma unroll
    for (int kb = 0; kb < 2; kb++)
      breg3[tap][kb] = *(const v8bf*)(B3t + (size_t)(ntw * 16 + l15) * 576
                                          + tap * 64 + kb * 32 + q * 8);
  const float bv3 = b3[ntw * 16 + l15];

  // produce act2 rel row t into ring slot s (act1 base slot == s as well,
  // since both rings are indexed rel-row % 6)
  auto produce = [&](int t, int s) {
    char* drow = a2r + s * A2ROWB;
    int pr = y0 + t;
    if (pr == 0 || pr == 257) {          // y zero-row (pad ring)
      int c = threadIdx.x;
      *(uint4*)(drow + (size_t)c * 16)         = make_uint4(0,0,0,0);
      *(uint4*)(drow + (size_t)(c + 256) * 16) = make_uint4(0,0,0,0);
      if (c < 16)
        *(uint4*)(drow + (size_t)(c + 512) * 16) = make_uint4(0,0,0,0);
      return;
    }
    v4f acc[5];
    #pragma unroll
    for (int m = 0; m < 5; m++) acc[m] = (v4f){bv2, bv2, bv2, bv2};
    #pragma unroll
    for (int tap = 0; tap < 9; tap++) {
      const int dy = tap / 3, dx = tap % 3;
      const char* srow = a1r + m6(s + dy) * A1ROWB;
      #pragma unroll
      for (int m = 0; m < 5; m++) {
        int j = m * 16 + l15 + dx;       // >67 over-reads: garbage px, unused
        v8bf af = *(const v8bf*)(srow + (size_t)swz(j * 4 + q) * 16);
        acc[m] = __builtin_amdgcn_mfma_f32_16x16x32_bf16(
            af, breg2[tap], acc[m], 0, 0, 0);
      }
    }
    const int ch = wave * 16 + l15;
    const int chunkoff = ch >> 3, byteoff = (ch & 7) * 2;
    #pragma unroll
    for (int m = 0; m < 5; m++) {
      #pragma unroll
      for (int r = 0; r < 4; r++) {
        int i = m * 16 + q * 4 + r;
        bool w = (m < 4) || (q == 0 && r < 2);     // i <= 65
        if (x0 == 0   && i == 0)  w = false;       // x-halo -> zeroed below
        if (x0 == 192 && i == 65) w = false;
        if (w) {
          __bf16 v = (__bf16)fmaxf(acc[m][r], 0.f);
          *(__bf16*)(drow + (size_t)swz(i * 8 + chunkoff) * 16 + byteoff) = v;
        }
      }
    }
    if (x0 == 0 && threadIdx.x < 8)                // zero slot 0 (real x=-1)
      *(uint4*)(drow + (size_t)swz(threadIdx.x) * 16) = make_uint4(0,0,0,0);
    if (x0 == 192 && threadIdx.x < 8)              // zero slot 65 (real x=256)
      *(uint4*)(drow + (size_t)swz(520 + threadIdx.x) * 16) = make_uint4(0,0,0,0);
  };

  // ---- prologue: stage act1 k=0..5, produce act2 rows 0,1 ----
  #pragma unroll
  for (int k = 0; k < 6; k++) stageA1(k, k);
  asm volatile("s_waitcnt vmcnt(0)" ::: "memory");
  __builtin_amdgcn_s_barrier();
  __builtin_amdgcn_sched_barrier(0);
  produce(0, 0);
  produce(1, 1);
  asm volatile("s_waitcnt lgkmcnt(0)" ::: "memory");
  __builtin_amdgcn_s_barrier();
  __builtin_amdgcn_sched_barrier(0);

  int sb = 0;                                     // (2*ps) % 6
  for (int ps = 0; ps < 4; ps++) {
    // stage ahead: act1 rel rows 2ps+6, 2ps+7 -> slots sb, sb+1 (rows 2ps,
    // 2ps+1 they overwrite were last read in iter ps-1, two barriers ago)
    if (2 * ps + 6 <= 11) stageA1(2 * ps + 6, sb);
    if (2 * ps + 7 <= 11) stageA1(2 * ps + 7, m6(sb + 1));

    // produce act2 rows 2ps+2, 2ps+3 (act1 staged & drained previous iter)
    produce(2 * ps + 2, m6(sb + 2));
    produce(2 * ps + 3, m6(sb + 3));
    asm volatile("s_waitcnt lgkmcnt(0)" ::: "memory");
    __builtin_amdgcn_s_barrier();
    __builtin_amdgcn_sched_barrier(0);

    // consume pair ps: act3 rows y0+2ps, y0+2ps+1 (conv3, row-paired)
    {
      v4f acc3[2][2];                             // [rr][mt]
      #pragma unroll
      for (int rr = 0; rr < 2; rr++)
        #pragma unroll
        for (int mt = 0; mt < 2; mt++)
          acc3[rr][mt] = (v4f){bv3, bv3, bv3, bv3};

      __builtin_amdgcn_s_setprio(1);
      #pragma unroll
      for (int t = 0; t < 4; t++) {
        const char* srow = a2r + m6(sb + t) * A2ROWB;
        #pragma unroll
        for (int dx = 0; dx < 3; dx++) {
          #pragma unroll
          for (int kb = 0; kb < 2; kb++) {
            v8bf af[2];
            #pragma unroll
            for (int mt = 0; mt < 2; mt++) {
              int P = Mh * 32 + mt * 16 + l15 + dx;   // 0..65
              af[mt] = *(const v8bf*)(srow + (size_t)swz(P * 8 + kb * 4 + q) * 16);
            }
            #pragma unroll
            for (int mt = 0; mt < 2; mt++) {
              if (t <= 2)
                acc3[0][mt] = __builtin_amdgcn_mfma_f32_16x16x32_bf16(
                    af[mt], breg3[t * 3 + dx][kb], acc3[0][mt], 0, 0, 0);
              if (t >= 1)
                acc3[1][mt] = __builtin_amdgcn_mfma_f32_16x16x32_bf16(
                    af[mt], breg3[(t - 1) * 3 + dx][kb], acc3[1][mt], 0, 0, 0);
            }
          }
        }
      }
      __builtin_amdgcn_s_setprio(0);

      #pragma unroll
      for (int rr = 0; rr < 2; rr++) {
        size_t rb = ((size_t)b * PADPLANE
                     + (size_t)(y0 + 2 * ps + rr + 1) * PADW + x0 + 1) * 32;
        #pragma unroll
        for (int mt = 0; mt < 2; mt++) {
          #pragma unroll
          for (int r = 0; r < 4; r++) {
            int px = Mh * 32 + mt * 16 + q * 4 + r;
            act3[rb + (size_t)px * 32 + ntw * 16 + l15] =
                (__bf16)fmaxf(acc3[rr][mt][r], 0.f);
          }
        }
      }
    }
    // counted drain: 4 stage ops (oldest) must land; 16 stores may fly
    asm volatile("s_waitcnt vmcnt(16)" ::: "memory");
    __builtin_amdgcn_s_barrier();
    __builtin_amdgcn_sched_barrier(0);
    sb = m6(sb + 2);
  }
}

// ---------------------------------------------------------------------------
// conv4 (32->1): LDS-staged act3 reads (round-3 form, measured neutral).
// ---------------------------------------------------------------------------
#define C4ROWB 16512   // 258 px * 32 ch * 2 B = 1032 chunks
__global__ __launch_bounds__(256, 2) void conv4_k(
    const __bf16* __restrict__ act3, const float* __restrict__ w4t,
    const float* __restrict__ b4, const float* __restrict__ sfp,
    float* __restrict__ dout)
{
  const int x = threadIdx.x, lane = threadIdx.x & 63, wave = threadIdx.x >> 6;
  const int y0 = blockIdx.x * 2, b = blockIdx.y;
  const float b4v = b4[0], sf = sfp[0];
  const __bf16* plane = act3 + (size_t)b * PADPLANE * 32;
  __shared__ __align__(16) char smem[4 * C4ROWB];

  #pragma unroll
  for (int r = 0; r < 4; r++) {
    const char* g = (const char*)(plane + (size_t)(y0 + r) * PADW * 32);
    char* lrow = smem + r * C4ROWB;
    #pragma unroll
    for (int k = 0; k < 4; k++) {
      int c = k * 256 + wave * 64 + lane;
      gl_lds(g + (size_t)swz(c) * 16, lrow + (k * 256 + wave * 64) * 16);
    }
    if (wave == 0 && lane < 8) {
      int c = 1024 + lane;
      gl_lds(g + (size_t)swz(c) * 16, lrow + 1024 * 16);
    }
  }
  asm volatile("s_waitcnt vmcnt(0)" ::: "memory");
  __builtin_amdgcn_s_barrier();

  float acc0 = b4v, acc1 = b4v;
  #pragma unroll
  for (int t = 0; t < 4; t++) {
    const char* srow = smem + t * C4ROWB;
    uint4 L[12];
    #pragma unroll
    for (int j = 0; j < 12; j++) {
      int chunk = (x + (j >> 2)) * 4 + (j & 3);
      L[j] = *(const uint4*)(srow + (size_t)swz(chunk) * 16);
    }
    #pragma unroll
    for (int j = 0; j < 12; j++) {
      const int dx = j >> 2, c0 = (j & 3) * 8;
      unsigned int uu[4] = {L[j].x, L[j].y, L[j].z, L[j].w};
      float f[8];
      #pragma unroll
      for (int k = 0; k < 4; k++) {
        f[2*k]   = __builtin_bit_cast(float, uu[k] << 16);
        f[2*k+1] = __builtin_bit_cast(float, uu[k] & 0xFFFF0000u);
      }
      if (t <= 2) {
        const float* wp = w4t + (t * 3 + dx) * 32 + c0;          // uniform
        #pragma unroll
        for (int k = 0; k < 8; k++) acc0 = fmaf(wp[k], f[k], acc0);
      }
      if (t >= 1) {
        const float* wp = w4t + ((t - 1) * 3 + dx) * 32 + c0;    // uniform
        #pragma unroll
        for (int k = 0; k < 8; k++) acc1 = fmaf(wp[k], f[k], acc1);
      }
    }
  }
  size_t p0 = ((size_t)b << 16) + (size_t)y0 * WIDTH + x;
  float vh0 = acc0 * sf, vh1 = acc1 * sf;
  dout[p0]                   = dout[524288 + p0] + vh0;          // outputs
  dout[2621440 + p0]         = vh0;                              // V_hat
  dout[p0 + WIDTH]           = dout[524288 + p0 + WIDTH] + vh1;
  dout[2621440 + p0 + WIDTH] = vh1;
}

// ---------------------------------------------------------------------------
extern "C" void kernel_launch(void* const* d_in, const int* in_sizes, int n_in,
                              void* d_out, int out_size, void* d_ws, size_t ws_size,
                              hipStream_t stream) {
  const float* inputs = (const float*)d_in[0];
  const float* H0     = (const float*)d_in[1];
  const float* C0     = (const float*)d_in[2];
  const float* c2     = (const float*)d_in[3];
  const float* sf     = (const float*)d_in[4];
  const float* w1     = (const float*)d_in[5];
  const float* b1     = (const float*)d_in[6];
  const float* w2     = (const float*)d_in[7];
  const float* b2     = (const float*)d_in[8];
  const float* w3     = (const float*)d_in[9];
  const float* b3     = (const float*)d_in[10];
  const float* w4     = (const float*)d_in[11];
  const float* b4     = (const float*)d_in[12];
  float* out = (float*)d_out;
  float* ws  = (float*)d_ws;

  float*  w1t  = ws;                               // 288 fp32
  float*  w4t  = ws + 288;                         // 288 fp32
  __bf16* B2t  = (__bf16*)(ws + 576);              // 18432 bf16
  __bf16* B3t  = (__bf16*)(ws + 9792);             // 18432 bf16
  __bf16* act1 = (__bf16*)(ws + 19008);            // 8*66564*32 bf16
  __bf16* act3 = act1 + (size_t)8 * PADPLANE * 32; // 8*66564*32 bf16

  wz_k<<<1175, 256, 0, stream>>>(w1, w2, w3, w4, w1t, B2t, B3t, w4t,
                                 act1, act3);
  prepconv1_k<<<dim3(256, 8), 256, 0, stream>>>(inputs, H0, C0, c2, sf,
                                                w1t, b1, out, act1);
  conv23_k<<<dim3(32, 4, 8), 256, 0, stream>>>(act1, B2t, b2, B3t, b3, act3);
  conv4_k<<<dim3(128, 8), 256, 0, stream>>>(act3, w4t, b4, sf, out);
}

// Round 5
// 172.701 us; speedup vs baseline: 1.0358x; 1.0358x over previous
//
#include <hip/hip_runtime.h>

#define PLANE 65536
#define WIDTH 256
#define PADW 258
#define PADPLANE 66564   // 258*258

typedef __bf16 v8bf __attribute__((ext_vector_type(8)));
typedef float  v4f  __attribute__((ext_vector_type(4)));

typedef const __attribute__((address_space(1))) unsigned int* gas_ptr;
typedef __attribute__((address_space(3))) unsigned int* las_ptr;

// async global->LDS, 16 B per lane; LDS dest = wave-uniform base + lane*16
__device__ __forceinline__ void gl_lds(const void* g, void* l) {
  __builtin_amdgcn_global_load_lds((gas_ptr)g, (las_ptr)l, 16, 0, 0);
}

// self-inverse 16B-chunk swizzle within 8-chunk groups; ~0 conflicts measured
__device__ __forceinline__ int swz(int c) {
  return (c & ~7) | ((c & 7) ^ ((c >> 3) & 7));
}

__device__ __forceinline__ int m6(int x) { return x >= 6 ? x - 6 : x; }

__device__ __forceinline__ unsigned int pack2(float a, float b) {
  __bf16 ba = (__bf16)a, bb = (__bf16)b;
  unsigned short sa = __builtin_bit_cast(unsigned short, ba);
  unsigned short sb = __builtin_bit_cast(unsigned short, bb);
  return (unsigned int)sa | ((unsigned int)sb << 16);
}

// ---------------------------------------------------------------------------
// wz_k: fused weight-prep + padding-ring zeroing (act1 + act3 only; act2 is
// LDS-resident inside conv23_k).
// ---------------------------------------------------------------------------
#define WT_N 37440                       // 288+18432+18432+288
#define ZR_N (8 * 1028 * 32)             // 16+16 uints per ring px
__global__ __launch_bounds__(256) void wz_k(
    const float* __restrict__ w1, const float* __restrict__ w2,
    const float* __restrict__ w3, const float* __restrict__ w4,
    float* __restrict__ w1t, __bf16* __restrict__ B2t,
    __bf16* __restrict__ B3t, float* __restrict__ w4t,
    __bf16* __restrict__ a1, __bf16* __restrict__ a3)
{
  int t = blockIdx.x * 256 + threadIdx.x;
  if (t < WT_N) {
    if (t < 288) {                       // w1: [32][1][9] -> [tap][32]
      int tap = t >> 5, cout = t & 31;
      w1t[t] = w1[cout * 9 + tap];
    }
    int t2 = t - 288;
    if (t2 >= 0 && t2 < 18432) {         // 64 x 288
      int cout = t2 / 288, k = t2 % 288;
      int tap = k / 32, cin = k % 32;
      B2t[t2] = (__bf16)w2[cout * 288 + cin * 9 + tap];
    }
    int t3 = t - (288 + 18432);
    if (t3 >= 0 && t3 < 18432) {         // 32 x 576
      int cout = t3 / 576, k = t3 % 576;
      int tap = k / 64, cin = k % 64;
      B3t[t3] = (__bf16)w3[cout * 576 + cin * 9 + tap];
    }
    int t4 = t - (288 + 18432 + 18432);
    if (t4 >= 0 && t4 < 288) {           // w4: [1][32][9] -> [tap][32]
      int tap = t4 >> 5, cin = t4 & 31;
      w4t[t4] = w4[cin * 9 + tap];
    }
    return;
  }
  int idx = t - WT_N;
  if (idx >= ZR_N) return;
  unsigned int* p;
  const int R1 = 8 * 1028 * 16;
  if (idx < R1) p = (unsigned int*)a1;
  else         { p = (unsigned int*)a3; idx -= R1; }
  int ch = idx & 15;
  int pr = idx >> 4;                 // 0 .. 8*1028-1
  int b = pr / 1028, r = pr % 1028;
  int y, x;
  if      (r < 258) { y = 0;           x = r; }
  else if (r < 516) { y = 257;         x = r - 258; }
  else if (r < 772) { y = r - 516 + 1; x = 0; }
  else              { y = r - 772 + 1; x = 257; }
  p[((size_t)b * PADPLANE + y * PADW + x) * 16 + ch] = 0;
}

// ---------------------------------------------------------------------------
// prepconv1_k: fused prep + conv1 (unchanged).
// ---------------------------------------------------------------------------
__global__ __launch_bounds__(256) void prepconv1_k(
    const float* __restrict__ inputs, const float* __restrict__ H0,
    const float* __restrict__ C0, const float* __restrict__ c2p,
    const float* __restrict__ sfp, const float* __restrict__ w1t,
    const float* __restrict__ b1, float* __restrict__ dout,
    __bf16* __restrict__ act1)
{
  const int x = threadIdx.x, y = blockIdx.x, b = blockIdx.y;
  const int p = b * PLANE + y * WIDTH + x;
  const float c2 = c2p[0], sf = sfp[0], rsf = 1.0f / sf;

  float iv[3][3], hv[3][3];
  #pragma unroll
  for (int dy = 0; dy < 3; dy++) {
    int yy = y + dy - 1;
    #pragma unroll
    for (int dx = 0; dx < 3; dx++) {
      int xx = x + dx - 1;
      bool ok = (yy >= 0 && yy < 256 && xx >= 0 && xx < 256);
      int pn = p + (dy - 1) * WIDTH + (dx - 1);
      iv[dy][dx] = ok ? inputs[pn] : 0.f;
      hv[dy][dx] = ok ? H0[pn]     : 0.f;
    }
  }
  const float in = iv[1][1], h0 = hv[1][1];
  const float c0a = C0[b * 131072 + y * WIDTH + x];
  float lap = iv[0][1] + iv[2][1] + iv[1][0] + iv[1][2] - 4.f * in;
  float Hv = 2.f * in - c0a + c2 * lap;
  float V  = in - h0;
  dout[524288 + p]  = Hv;                               // H
  dout[2097152 + p] = V;                                // V
  dout[1048576 + b * 131072 + y * WIDTH + x]         = in;   // C_new[:,0]
  dout[1048576 + b * 131072 + 65536 + y * WIDTH + x] = c0a;  // C_new[:,1]

  float acc[32];
  #pragma unroll
  for (int i = 0; i < 32; i++) acc[i] = b1[i];
  #pragma unroll
  for (int tap = 0; tap < 9; tap++) {
    float v = (iv[tap / 3][tap % 3] - hv[tap / 3][tap % 3]) * rsf;
    const float* wp = w1t + tap * 32;                   // uniform
    #pragma unroll
    for (int i = 0; i < 32; i++) acc[i] = fmaf(wp[i], v, acc[i]);
  }
  unsigned int u[16];
  #pragma unroll
  for (int j = 0; j < 16; j++)
    u[j] = pack2(fmaxf(acc[2*j], 0.f), fmaxf(acc[2*j+1], 0.f));
  size_t pa = ((size_t)b * PADPLANE + (y+1) * PADW + (x+1)) * 32;
  uint4* op = reinterpret_cast<uint4*>(act1 + pa);
  #pragma unroll
  for (int j = 0; j < 4; j++)
    op[j] = make_uint4(u[4*j], u[4*j+1], u[4*j+2], u[4*j+3]);
}

// ---------------------------------------------------------------------------
// conv23_k: FUSED conv2 (32->64) + conv3 (64->32); act2 stays in LDS.
//
// ROUND-5 CHANGES (from r4 PMC: MfmaUtil 28.5 = arithmetic floor/2.5,
// VALUBusy 28.5, 2.44M bank conflicts localized to produce's b16 scatter):
//  1. produce MFMA operand SWAP: acc[m] = mfma(breg2, af) -> D[cout][px].
//     Lane now holds px = m*16+l15 with 4 CONSECUTIVE channels
//     (ch = wave*16+q*4+r): epilogue = 5 aligned ds_write_b64 (pack2 x2)
//     instead of 20 conflicted ds_write_b16 (bank-balanced: 4 dwords/bank).
//     Fragment loads unchanged (A/B per-lane layouts are symmetric);
//     per-output accumulation order unchanged -> bit-identical act2.
//  2. ROWS 8 -> 16 (grid y 32 -> 16, 512 blocks = 2/CU): halo recompute
//     1.29x -> 1.16x, prologue amortized 2x. Ring indices are sb-relative
//     (sb in {0,2,4}) so 6-slot m6 rings stay correct.
// ---------------------------------------------------------------------------
#define A1ROWB 4352   // 68 px * 32 ch * 2 B = 272 chunks
#define A2ROWB 8448   // 66 px * 64 ch * 2 B = 528 chunks
__global__ __launch_bounds__(256, 2) void conv23_k(
    const __bf16* __restrict__ act1, const __bf16* __restrict__ B2t,
    const float* __restrict__ b2, const __bf16* __restrict__ B3t,
    const float* __restrict__ b3, __bf16* __restrict__ act3)
{
  const int lane = threadIdx.x & 63, wave = threadIdx.x >> 6;
  const int l15 = lane & 15, q = lane >> 4;
  const int y0 = blockIdx.x * 16, xt = blockIdx.y, b = blockIdx.z;
  const int x0 = xt * 64;
  __shared__ __align__(16) char smem[6 * A2ROWB + 6 * A1ROWB + 1024];
  char* a2r = smem;                       // act2 ring
  char* a1r = smem + 6 * A2ROWB;          // act1 ring (+1KB pad for ragged
                                          //  M-tile over-reads)
  const __bf16* plane = act1 + (size_t)b * PADPLANE * 32;

  // stage act1 rel row k (padded row y0-1+k, clamped) into ring slot
  auto stageA1 = [&](int k, int slot) {
    int a = y0 - 1 + k;
    a = a < 0 ? 0 : (a > 257 ? 257 : a);
    const char* g = (const char*)(plane + ((size_t)a * PADW + x0 - 1) * 32);
    char* lrow = a1r + slot * A1ROWB;
    const int base = wave * 68;
    gl_lds(g + (size_t)swz(base + lane) * 16, lrow + base * 16);
    if (lane < 4)
      gl_lds(g + (size_t)swz(base + 64 + lane) * 16, lrow + (base + 64) * 16);
  };

  // conv2 weights: this wave's 16 couts (fragment load unchanged; as the
  // A-operand now, lane l15 = cout row, q*8 = cin-block — same data)
  v8bf breg2[9];
  #pragma unroll
  for (int tap = 0; tap < 9; tap++)
    breg2[tap] = *(const v8bf*)(B2t + (size_t)(wave * 16 + l15) * 288
                                    + tap * 32 + q * 8);
  const v4f bv2 = *(const v4f*)(b2 + wave * 16 + q * 4);   // 4 couts/lane

  // conv3 weights: wave = (Mh = wave>>1 px-half, ntw = wave&1 cout-half)
  const int Mh = wave >> 1, ntw = wave & 1;
  v8bf breg3[9][2];
  #pragma unroll
  for (int tap = 0; tap < 9; tap++)
    #pragma unroll
    for (int kb = 0; kb < 2; kb++)
      breg3[tap][kb] = *(const v8bf*)(B3t + (size_t)(ntw * 16 + l15) * 576
                                          + tap * 64 + kb * 32 + q * 8);
  const float bv3 = b3[ntw * 16 + l15];

  // produce act2 rel row t into ring slot s
  auto produce = [&](int t, int s) {
    char* drow = a2r + s * A2ROWB;
    int pr = y0 + t;
    if (pr == 0 || pr == 257) {          // y zero-row (pad ring)
      int c = threadIdx.x;
      *(uint4*)(drow + (size_t)c * 16)         = make_uint4(0,0,0,0);
      *(uint4*)(drow + (size_t)(c + 256) * 16) = make_uint4(0,0,0,0);
      if (c < 16)
        *(uint4*)(drow + (size_t)(c + 512) * 16) = make_uint4(0,0,0,0);
      return;
    }
    v4f acc[5];
    #pragma unroll
    for (int m = 0; m < 5; m++) acc[m] = bv2;
    #pragma unroll
    for (int tap = 0; tap < 9; tap++) {
      const int dy = tap / 3, dx = tap % 3;
      const char* srow = a1r + m6(s + dy) * A1ROWB;
      #pragma unroll
      for (int m = 0; m < 5; m++) {
        int j = m * 16 + l15 + dx;       // >67 over-reads: garbage px, unused
        v8bf af = *(const v8bf*)(srow + (size_t)swz(j * 4 + q) * 16);
        acc[m] = __builtin_amdgcn_mfma_f32_16x16x32_bf16(
            breg2[tap], af, acc[m], 0, 0, 0);          // SWAPPED: D[cout][px]
      }
    }
    // lane holds px = m*16+l15, ch = wave*16 + q*4 + (0..3): one b64/m-tile
    const int c = wave * 2 + (q >> 1), boff = (q & 1) * 8;
    #pragma unroll
    for (int m = 0; m < 5; m++) {
      int px = m * 16 + l15;
      bool w = (m < 4) || (l15 < 2);                   // px <= 65
      if (x0 == 0   && px == 0)  w = false;            // x-halo -> zeroed
      if (x0 == 192 && px == 65) w = false;
      if (w) {
        unsigned int lo = pack2(fmaxf(acc[m][0], 0.f), fmaxf(acc[m][1], 0.f));
        unsigned int hi = pack2(fmaxf(acc[m][2], 0.f), fmaxf(acc[m][3], 0.f));
        *(uint2*)(drow + (size_t)swz(px * 8 + c) * 16 + boff)
            = make_uint2(lo, hi);
      }
    }
    if (x0 == 0 && threadIdx.x < 8)                // zero slot 0 (real x=-1)
      *(uint4*)(drow + (size_t)swz(threadIdx.x) * 16) = make_uint4(0,0,0,0);
    if (x0 == 192 && threadIdx.x < 8)              // zero slot 65 (real x=256)
      *(uint4*)(drow + (size_t)swz(520 + threadIdx.x) * 16) = make_uint4(0,0,0,0);
  };

  // ---- prologue: stage act1 k=0..5, produce act2 rows 0,1 ----
  #pragma unroll
  for (int k = 0; k < 6; k++) stageA1(k, k);
  asm volatile("s_waitcnt vmcnt(0)" ::: "memory");
  __builtin_amdgcn_s_barrier();
  __builtin_amdgcn_sched_barrier(0);
  produce(0, 0);
  produce(1, 1);
  asm volatile("s_waitcnt lgkmcnt(0)" ::: "memory");
  __builtin_amdgcn_s_barrier();
  __builtin_amdgcn_sched_barrier(0);

  int sb = 0;                                     // (2*ps) % 6
  for (int ps = 0; ps < 8; ps++) {
    // stage ahead: act1 rel rows 2ps+6, 2ps+7 (overwrite slots of rows
    // 2ps, 2ps+1 — last read in iter ps-1, behind two barriers)
    if (2 * ps + 6 <= 19) stageA1(2 * ps + 6, sb);
    if (2 * ps + 7 <= 19) stageA1(2 * ps + 7, m6(sb + 1));

    // produce act2 rows 2ps+2, 2ps+3 (act1 staged & drained previous iter)
    produce(2 * ps + 2, m6(sb + 2));
    produce(2 * ps + 3, m6(sb + 3));
    asm volatile("s_waitcnt lgkmcnt(0)" ::: "memory");
    __builtin_amdgcn_s_barrier();
    __builtin_amdgcn_sched_barrier(0);

    // consume pair ps: act3 rows y0+2ps, y0+2ps+1 (conv3, row-paired)
    {
      v4f acc3[2][2];                             // [rr][mt]
      #pragma unroll
      for (int rr = 0; rr < 2; rr++)
        #pragma unroll
        for (int mt = 0; mt < 2; mt++)
          acc3[rr][mt] = (v4f){bv3, bv3, bv3, bv3};

      __builtin_amdgcn_s_setprio(1);
      #pragma unroll
      for (int t = 0; t < 4; t++) {
        const char* srow = a2r + m6(sb + t) * A2ROWB;
        #pragma unroll
        for (int dx = 0; dx < 3; dx++) {
          #pragma unroll
          for (int kb = 0; kb < 2; kb++) {
            v8bf af[2];
            #pragma unroll
            for (int mt = 0; mt < 2; mt++) {
              int P = Mh * 32 + mt * 16 + l15 + dx;   // 0..65
              af[mt] = *(const v8bf*)(srow + (size_t)swz(P * 8 + kb * 4 + q) * 16);
            }
            #pragma unroll
            for (int mt = 0; mt < 2; mt++) {
              if (t <= 2)
                acc3[0][mt] = __builtin_amdgcn_mfma_f32_16x16x32_bf16(
                    af[mt], breg3[t * 3 + dx][kb], acc3[0][mt], 0, 0, 0);
              if (t >= 1)
                acc3[1][mt] = __builtin_amdgcn_mfma_f32_16x16x32_bf16(
                    af[mt], breg3[(t - 1) * 3 + dx][kb], acc3[1][mt], 0, 0, 0);
            }
          }
        }
      }
      __builtin_amdgcn_s_setprio(0);

      #pragma unroll
      for (int rr = 0; rr < 2; rr++) {
        size_t rb = ((size_t)b * PADPLANE
                     + (size_t)(y0 + 2 * ps + rr + 1) * PADW + x0 + 1) * 32;
        #pragma unroll
        for (int mt = 0; mt < 2; mt++) {
          #pragma unroll
          for (int r = 0; r < 4; r++) {
            int px = Mh * 32 + mt * 16 + q * 4 + r;
            act3[rb + (size_t)px * 32 + ntw * 16 + l15] =
                (__bf16)fmaxf(acc3[rr][mt][r], 0.f);
          }
        }
      }
    }
    // counted drain: 4 stage ops (oldest) must land; 16 stores may fly
    asm volatile("s_waitcnt vmcnt(16)" ::: "memory");
    __builtin_amdgcn_s_barrier();
    __builtin_amdgcn_sched_barrier(0);
    sb = m6(sb + 2);
  }
}

// ---------------------------------------------------------------------------
// conv4 (32->1): LDS-staged act3 reads (round-3 form, measured neutral).
// ---------------------------------------------------------------------------
#define C4ROWB 16512   // 258 px * 32 ch * 2 B = 1032 chunks
__global__ __launch_bounds__(256, 2) void conv4_k(
    const __bf16* __restrict__ act3, const float* __restrict__ w4t,
    const float* __restrict__ b4, const float* __restrict__ sfp,
    float* __restrict__ dout)
{
  const int x = threadIdx.x, lane = threadIdx.x & 63, wave = threadIdx.x >> 6;
  const int y0 = blockIdx.x * 2, b = blockIdx.y;
  const float b4v = b4[0], sf = sfp[0];
  const __bf16* plane = act3 + (size_t)b * PADPLANE * 32;
  __shared__ __align__(16) char smem[4 * C4ROWB];

  #pragma unroll
  for (int r = 0; r < 4; r++) {
    const char* g = (const char*)(plane + (size_t)(y0 + r) * PADW * 32);
    char* lrow = smem + r * C4ROWB;
    #pragma unroll
    for (int k = 0; k < 4; k++) {
      int c = k * 256 + wave * 64 + lane;
      gl_lds(g + (size_t)swz(c) * 16, lrow + (k * 256 + wave * 64) * 16);
    }
    if (wave == 0 && lane < 8) {
      int c = 1024 + lane;
      gl_lds(g + (size_t)swz(c) * 16, lrow + 1024 * 16);
    }
  }
  asm volatile("s_waitcnt vmcnt(0)" ::: "memory");
  __builtin_amdgcn_s_barrier();

  float acc0 = b4v, acc1 = b4v;
  #pragma unroll
  for (int t = 0; t < 4; t++) {
    const char* srow = smem + t * C4ROWB;
    uint4 L[12];
    #pragma unroll
    for (int j = 0; j < 12; j++) {
      int chunk = (x + (j >> 2)) * 4 + (j & 3);
      L[j] = *(const uint4*)(srow + (size_t)swz(chunk) * 16);
    }
    #pragma unroll
    for (int j = 0; j < 12; j++) {
      const int dx = j >> 2, c0 = (j & 3) * 8;
      unsigned int uu[4] = {L[j].x, L[j].y, L[j].z, L[j].w};
      float f[8];
      #pragma unroll
      for (int k = 0; k < 4; k++) {
        f[2*k]   = __builtin_bit_cast(float, uu[k] << 16);
        f[2*k+1] = __builtin_bit_cast(float, uu[k] & 0xFFFF0000u);
      }
      if (t <= 2) {
        const float* wp = w4t + (t * 3 + dx) * 32 + c0;          // uniform
        #pragma unroll
        for (int k = 0; k < 8; k++) acc0 = fmaf(wp[k], f[k], acc0);
      }
      if (t >= 1) {
        const float* wp = w4t + ((t - 1) * 3 + dx) * 32 + c0;    // uniform
        #pragma unroll
        for (int k = 0; k < 8; k++) acc1 = fmaf(wp[k], f[k], acc1);
      }
    }
  }
  size_t p0 = ((size_t)b << 16) + (size_t)y0 * WIDTH + x;
  float vh0 = acc0 * sf, vh1 = acc1 * sf;
  dout[p0]                   = dout[524288 + p0] + vh0;          // outputs
  dout[2621440 + p0]         = vh0;                              // V_hat
  dout[p0 + WIDTH]           = dout[524288 + p0 + WIDTH] + vh1;
  dout[2621440 + p0 + WIDTH] = vh1;
}

// ---------------------------------------------------------------------------
extern "C" void kernel_launch(void* const* d_in, const int* in_sizes, int n_in,
                              void* d_out, int out_size, void* d_ws, size_t ws_size,
                              hipStream_t stream) {
  const float* inputs = (const float*)d_in[0];
  const float* H0     = (const float*)d_in[1];
  const float* C0     = (const float*)d_in[2];
  const float* c2     = (const float*)d_in[3];
  const float* sf     = (const float*)d_in[4];
  const float* w1     = (const float*)d_in[5];
  const float* b1     = (const float*)d_in[6];
  const float* w2     = (const float*)d_in[7];
  const float* b2     = (const float*)d_in[8];
  const float* w3     = (const float*)d_in[9];
  const float* b3     = (const float*)d_in[10];
  const float* w4     = (const float*)d_in[11];
  const float* b4     = (const float*)d_in[12];
  float* out = (float*)d_out;
  float* ws  = (float*)d_ws;

  float*  w1t  = ws;                               // 288 fp32
  float*  w4t  = ws + 288;                         // 288 fp32
  __bf16* B2t  = (__bf16*)(ws + 576);              // 18432 bf16
  __bf16* B3t  = (__bf16*)(ws + 9792);             // 18432 bf16
  __bf16* act1 = (__bf16*)(ws + 19008);            // 8*66564*32 bf16
  __bf16* act3 = act1 + (size_t)8 * PADPLANE * 32; // 8*66564*32 bf16

  wz_k<<<1175, 256, 0, stream>>>(w1, w2, w3, w4, w1t, B2t, B3t, w4t,
                                 act1, act3);
  prepconv1_k<<<dim3(256, 8), 256, 0, stream>>>(inputs, H0, C0, c2, sf,
                                                w1t, b1, out, act1);
  conv23_k<<<dim3(16, 4, 8), 256, 0, stream>>>(act1, B2t, b2, B3t, b3, act3);
  conv4_k<<<dim3(128, 8), 256, 0, stream>>>(act3, w4t, b4, sf, out);
}

// Round 6
// 164.467 us; speedup vs baseline: 1.0877x; 1.0501x over previous
//
#include <hip/hip_runtime.h>

#define PLANE 65536
#define WIDTH 256
#define PADW 258
#define PADPLANE 66564   // 258*258

typedef __bf16 v8bf __attribute__((ext_vector_type(8)));
typedef float  v4f  __attribute__((ext_vector_type(4)));

typedef const __attribute__((address_space(1))) unsigned int* gas_ptr;
typedef __attribute__((address_space(3))) unsigned int* las_ptr;

// async global->LDS, 16 B per lane; LDS dest = wave-uniform base + lane*16
__device__ __forceinline__ void gl_lds(const void* g, void* l) {
  __builtin_amdgcn_global_load_lds((gas_ptr)g, (las_ptr)l, 16, 0, 0);
}

// self-inverse 16B-chunk swizzle within 8-chunk groups
__device__ __forceinline__ int swz(int c) {
  return (c & ~7) | ((c & 7) ^ ((c >> 3) & 7));
}

__device__ __forceinline__ int m6(int x) { return x >= 6 ? x - 6 : x; }

__device__ __forceinline__ unsigned int pack2(float a, float b) {
  __bf16 ba = (__bf16)a, bb = (__bf16)b;
  unsigned short sa = __builtin_bit_cast(unsigned short, ba);
  unsigned short sb = __builtin_bit_cast(unsigned short, bb);
  return (unsigned int)sa | ((unsigned int)sb << 16);
}

// ---------------------------------------------------------------------------
// wz_k: fused weight-prep + padding-ring zeroing (act1 + act3 only).
// ---------------------------------------------------------------------------
#define WT_N 37440                       // 288+18432+18432+288
#define ZR_N (8 * 1028 * 32)             // 16+16 uints per ring px
__global__ __launch_bounds__(256) void wz_k(
    const float* __restrict__ w1, const float* __restrict__ w2,
    const float* __restrict__ w3, const float* __restrict__ w4,
    float* __restrict__ w1t, __bf16* __restrict__ B2t,
    __bf16* __restrict__ B3t, float* __restrict__ w4t,
    __bf16* __restrict__ a1, __bf16* __restrict__ a3)
{
  int t = blockIdx.x * 256 + threadIdx.x;
  if (t < WT_N) {
    if (t < 288) {                       // w1: [32][1][9] -> [tap][32]
      int tap = t >> 5, cout = t & 31;
      w1t[t] = w1[cout * 9 + tap];
    }
    int t2 = t - 288;
    if (t2 >= 0 && t2 < 18432) {         // 64 x 288
      int cout = t2 / 288, k = t2 % 288;
      int tap = k / 32, cin = k % 32;
      B2t[t2] = (__bf16)w2[cout * 288 + cin * 9 + tap];
    }
    int t3 = t - (288 + 18432);
    if (t3 >= 0 && t3 < 18432) {         // 32 x 576
      int cout = t3 / 576, k = t3 % 576;
      int tap = k / 64, cin = k % 64;
      B3t[t3] = (__bf16)w3[cout * 576 + cin * 9 + tap];
    }
    int t4 = t - (288 + 18432 + 18432);
    if (t4 >= 0 && t4 < 288) {           // w4: [1][32][9] -> [tap][32]
      int tap = t4 >> 5, cin = t4 & 31;
      w4t[t4] = w4[cin * 9 + tap];
    }
    return;
  }
  int idx = t - WT_N;
  if (idx >= ZR_N) return;
  unsigned int* p;
  const int R1 = 8 * 1028 * 16;
  if (idx < R1) p = (unsigned int*)a1;
  else         { p = (unsigned int*)a3; idx -= R1; }
  int ch = idx & 15;
  int pr = idx >> 4;                 // 0 .. 8*1028-1
  int b = pr / 1028, r = pr % 1028;
  int y, x;
  if      (r < 258) { y = 0;           x = r; }
  else if (r < 516) { y = 257;         x = r - 258; }
  else if (r < 772) { y = r - 516 + 1; x = 0; }
  else              { y = r - 772 + 1; x = 257; }
  p[((size_t)b * PADPLANE + y * PADW + x) * 16 + ch] = 0;
}

// ---------------------------------------------------------------------------
// prepconv1_k: fused prep + conv1 (unchanged).
// ---------------------------------------------------------------------------
__global__ __launch_bounds__(256) void prepconv1_k(
    const float* __restrict__ inputs, const float* __restrict__ H0,
    const float* __restrict__ C0, const float* __restrict__ c2p,
    const float* __restrict__ sfp, const float* __restrict__ w1t,
    const float* __restrict__ b1, float* __restrict__ dout,
    __bf16* __restrict__ act1)
{
  const int x = threadIdx.x, y = blockIdx.x, b = blockIdx.y;
  const int p = b * PLANE + y * WIDTH + x;
  const float c2 = c2p[0], sf = sfp[0], rsf = 1.0f / sf;

  float iv[3][3], hv[3][3];
  #pragma unroll
  for (int dy = 0; dy < 3; dy++) {
    int yy = y + dy - 1;
    #pragma unroll
    for (int dx = 0; dx < 3; dx++) {
      int xx = x + dx - 1;
      bool ok = (yy >= 0 && yy < 256 && xx >= 0 && xx < 256);
      int pn = p + (dy - 1) * WIDTH + (dx - 1);
      iv[dy][dx] = ok ? inputs[pn] : 0.f;
      hv[dy][dx] = ok ? H0[pn]     : 0.f;
    }
  }
  const float in = iv[1][1], h0 = hv[1][1];
  const float c0a = C0[b * 131072 + y * WIDTH + x];
  float lap = iv[0][1] + iv[2][1] + iv[1][0] + iv[1][2] - 4.f * in;
  float Hv = 2.f * in - c0a + c2 * lap;
  float V  = in - h0;
  dout[524288 + p]  = Hv;                               // H
  dout[2097152 + p] = V;                                // V
  dout[1048576 + b * 131072 + y * WIDTH + x]         = in;   // C_new[:,0]
  dout[1048576 + b * 131072 + 65536 + y * WIDTH + x] = c0a;  // C_new[:,1]

  float acc[32];
  #pragma unroll
  for (int i = 0; i < 32; i++) acc[i] = b1[i];
  #pragma unroll
  for (int tap = 0; tap < 9; tap++) {
    float v = (iv[tap / 3][tap % 3] - hv[tap / 3][tap % 3]) * rsf;
    const float* wp = w1t + tap * 32;                   // uniform
    #pragma unroll
    for (int i = 0; i < 32; i++) acc[i] = fmaf(wp[i], v, acc[i]);
  }
  unsigned int u[16];
  #pragma unroll
  for (int j = 0; j < 16; j++)
    u[j] = pack2(fmaxf(acc[2*j], 0.f), fmaxf(acc[2*j+1], 0.f));
  size_t pa = ((size_t)b * PADPLANE + (y+1) * PADW + (x+1)) * 32;
  uint4* op = reinterpret_cast<uint4*>(act1 + pa);
  #pragma unroll
  for (int j = 0; j < 4; j++)
    op[j] = make_uint4(u[4*j], u[4*j+1], u[4*j+2], u[4*j+3]);
}

// ---------------------------------------------------------------------------
// conv23_k: FUSED conv2+conv3 with PRODUCER/CONSUMER WAVE SPECIALIZATION.
//
// r5 PMC: MfmaUtil 31 / VALUBusy 28 / LDS ~26% — no pipe saturated, 8
// waves/CU, 2 full-drain barriers per pair: sync/latency-bound.
// Now: 512-thread blocks; waves 0-3 PRODUCE (conv2, cout-split, breg2 only),
// waves 4-7 CONSUME (conv3, px/cout-split, breg3 only) -> 16 waves/CU,
// produce and consume overlap, ONE barrier per pair-step.
//
// Hazard table (all >=1 barrier of separation):
//  - a2: C reads rows 2ps..2ps+3, P writes 2ps+4,5 -> 6 consecutive rows on
//    a 6-slot ring: disjoint within iter; P row written iter ps first read
//    by C iter ps+2; C-read slots overwritten by P iter ps+1.
//  - a1 overwrite: iter ps stages into slots of rows 2ps+2,3, last read by
//    produce in iter ps-1.
//  - a1 visibility: vmcnt is PER-WAVE -> each P-wave drains its own gl_lds
//    (vmcnt(0)) BEFORE the iter-end barrier; reads happen next iter.
//    Drain is free: issued at iter top, ~90 MFMAs in between (T14).
//  - P's ds_writes: lgkmcnt(0) before the same barrier.
// C-waves have NO vmcnt waits (stores never drained).
// ---------------------------------------------------------------------------
#define A1ROWB 4352   // 68 px * 32 ch * 2 B = 272 chunks
#define A2ROWB 8448   // 66 px * 64 ch * 2 B = 528 chunks
__global__ __launch_bounds__(512, 4) void conv23_k(
    const __bf16* __restrict__ act1, const __bf16* __restrict__ B2t,
    const float* __restrict__ b2, const __bf16* __restrict__ B3t,
    const float* __restrict__ b3, __bf16* __restrict__ act3)
{
  const int lane = threadIdx.x & 63, wave = threadIdx.x >> 6;
  const int l15 = lane & 15, q = lane >> 4;
  const int y0 = blockIdx.x * 16, xt = blockIdx.y, b = blockIdx.z;
  const int x0 = xt * 64;
  __shared__ __align__(16) char smem[6 * A2ROWB + 6 * A1ROWB + 1024];
  char* a2r = smem;                       // act2 ring (6 slots)
  char* a1r = smem + 6 * A2ROWB;          // act1 ring (6 slots; +1KB pad for
                                          //  ragged m-tile over-reads)
  const __bf16* plane = act1 + (size_t)b * PADPLANE * 32;

  if (wave < 4) {
    // ------------------------- PRODUCER (conv2) -------------------------
    auto stageA1 = [&](int k, int slot) {  // a1 rel row k = padded y0-1+k
      int a = y0 - 1 + k;
      a = a < 0 ? 0 : (a > 257 ? 257 : a);
      const char* g = (const char*)(plane + ((size_t)a * PADW + x0 - 1) * 32);
      char* lrow = a1r + slot * A1ROWB;
      const int base = wave * 68;
      gl_lds(g + (size_t)swz(base + lane) * 16, lrow + base * 16);
      if (lane < 4)
        gl_lds(g + (size_t)swz(base + 64 + lane) * 16, lrow + (base + 64) * 16);
    };

    v8bf breg2[9];                         // this wave's 16 couts
    #pragma unroll
    for (int tap = 0; tap < 9; tap++)
      breg2[tap] = *(const v8bf*)(B2t + (size_t)(wave * 16 + l15) * 288
                                      + tap * 32 + q * 8);
    const v4f bv2 = *(const v4f*)(b2 + wave * 16 + q * 4);

    // produce a2 rel row t (padded act2 row y0+t) into ring slot s = t%6
    auto produce = [&](int t, int s) {
      char* drow = a2r + s * A2ROWB;
      int pr = y0 + t;
      if (pr == 0 || pr == 257) {          // y zero-row (pad ring)
        int c = threadIdx.x;               // P-group: 0..255
        *(uint4*)(drow + (size_t)c * 16)         = make_uint4(0,0,0,0);
        *(uint4*)(drow + (size_t)(c + 256) * 16) = make_uint4(0,0,0,0);
        if (c < 16)
          *(uint4*)(drow + (size_t)(c + 512) * 16) = make_uint4(0,0,0,0);
        return;
      }
      v4f acc[5];
      #pragma unroll
      for (int m = 0; m < 5; m++) acc[m] = bv2;
      #pragma unroll
      for (int tap = 0; tap < 9; tap++) {
        const int dy = tap / 3, dx = tap % 3;
        const char* srow = a1r + m6(s + dy) * A1ROWB;
        #pragma unroll
        for (int m = 0; m < 5; m++) {
          int j = m * 16 + l15 + dx;       // >67 over-reads: garbage, unused
          v8bf af = *(const v8bf*)(srow + (size_t)swz(j * 4 + q) * 16);
          acc[m] = __builtin_amdgcn_mfma_f32_16x16x32_bf16(
              breg2[tap], af, acc[m], 0, 0, 0);        // D[cout][px]
        }
      }
      const int c = wave * 2 + (q >> 1), boff = (q & 1) * 8;
      #pragma unroll
      for (int m = 0; m < 5; m++) {
        int px = m * 16 + l15;
        bool w = (m < 4) || (l15 < 2);                 // px <= 65
        if (x0 == 0   && px == 0)  w = false;          // x-halo -> zeroed
        if (x0 == 192 && px == 65) w = false;
        if (w) {
          unsigned int lo = pack2(fmaxf(acc[m][0], 0.f), fmaxf(acc[m][1], 0.f));
          unsigned int hi = pack2(fmaxf(acc[m][2], 0.f), fmaxf(acc[m][3], 0.f));
          *(uint2*)(drow + (size_t)swz(px * 8 + c) * 16 + boff)
              = make_uint2(lo, hi);
        }
      }
      if (x0 == 0 && threadIdx.x < 8)              // zero px slot 0 (x=-1)
        *(uint4*)(drow + (size_t)swz(threadIdx.x) * 16) = make_uint4(0,0,0,0);
      if (x0 == 192 && threadIdx.x < 8)            // zero px slot 65 (x=256)
        *(uint4*)(drow + (size_t)swz(520 + threadIdx.x) * 16) = make_uint4(0,0,0,0);
    };

    // prologue: a1 rows 0..5; produce a2 rows 0..3; a1 rows 6,7
    #pragma unroll
    for (int k = 0; k < 6; k++) stageA1(k, k);
    asm volatile("s_waitcnt vmcnt(0)" ::: "memory");
    __builtin_amdgcn_s_barrier();                         // bar 1
    __builtin_amdgcn_sched_barrier(0);
    produce(0, 0); produce(1, 1); produce(2, 2); produce(3, 3);
    asm volatile("s_waitcnt lgkmcnt(0)" ::: "memory");
    __builtin_amdgcn_s_barrier();                         // bar 2
    __builtin_amdgcn_sched_barrier(0);
    stageA1(6, 0); stageA1(7, 1);
    asm volatile("s_waitcnt vmcnt(0)" ::: "memory");
    __builtin_amdgcn_s_barrier();                         // bar 3
    __builtin_amdgcn_sched_barrier(0);

    int sb = 2;                                           // (2ps+2)%6
    for (int ps = 0; ps < 8; ps++) {
      // stage a1 rows 2ps+8,9 (clamped; clamp rows land in free slots)
      int r0 = 2 * ps + 8, r1 = 2 * ps + 9;
      stageA1(r0 > 19 ? 19 : r0, sb);
      stageA1(r1 > 19 ? 19 : r1, m6(sb + 1));
      // produce a2 rows 2ps+4,5 (a1 rows 2ps+4..2ps+7 staged+drained)
      if (2 * ps + 4 <= 17) produce(2 * ps + 4, m6(sb + 2));
      if (2 * ps + 5 <= 17) produce(2 * ps + 5, m6(sb + 3));
      // own-wave drains BEFORE the shared barrier (cross-wave visibility)
      asm volatile("s_waitcnt vmcnt(0) lgkmcnt(0)" ::: "memory");
      __builtin_amdgcn_s_barrier();                       // bar 4+ps
      __builtin_amdgcn_sched_barrier(0);
      sb = m6(sb + 2);
    }
  } else {
    // ------------------------- CONSUMER (conv3) -------------------------
    const int cw = wave - 4;
    const int Mh = cw >> 1, ntw = cw & 1;
    v8bf breg3[9][2];                          // tap, kb
    #pragma unroll
    for (int tap = 0; tap < 9; tap++)
      #pragma unroll
      for (int kb = 0; kb < 2; kb++)
        breg3[tap][kb] = *(const v8bf*)(B3t + (size_t)(ntw * 16 + l15) * 576
                                            + tap * 64 + kb * 32 + q * 8);
    const float bv3 = b3[ntw * 16 + l15];

    __builtin_amdgcn_s_barrier();                         // bar 1
    __builtin_amdgcn_s_barrier();                         // bar 2
    __builtin_amdgcn_s_barrier();                         // bar 3

    int sc = 0;                                           // (2ps)%6
    for (int ps = 0; ps < 8; ps++) {
      v4f acc3[2][2];                             // [rr][mt]
      #pragma unroll
      for (int rr = 0; rr < 2; rr++)
        #pragma unroll
        for (int mt = 0; mt < 2; mt++)
          acc3[rr][mt] = (v4f){bv3, bv3, bv3, bv3};

      __builtin_amdgcn_s_setprio(1);
      #pragma unroll
      for (int t = 0; t < 4; t++) {
        const char* srow = a2r + m6(sc + t) * A2ROWB;
        #pragma unroll
        for (int dx = 0; dx < 3; dx++) {
          #pragma unroll
          for (int kb = 0; kb < 2; kb++) {
            v8bf af[2];
            #pragma unroll
            for (int mt = 0; mt < 2; mt++) {
              int P = Mh * 32 + mt * 16 + l15 + dx;   // 0..65
              af[mt] = *(const v8bf*)(srow + (size_t)swz(P * 8 + kb * 4 + q) * 16);
            }
            #pragma unroll
            for (int mt = 0; mt < 2; mt++) {
              if (t <= 2)
                acc3[0][mt] = __builtin_amdgcn_mfma_f32_16x16x32_bf16(
                    af[mt], breg3[t * 3 + dx][kb], acc3[0][mt], 0, 0, 0);
              if (t >= 1)
                acc3[1][mt] = __builtin_amdgcn_mfma_f32_16x16x32_bf16(
                    af[mt], breg3[(t - 1) * 3 + dx][kb], acc3[1][mt], 0, 0, 0);
            }
          }
        }
      }
      __builtin_amdgcn_s_setprio(0);

      #pragma unroll
      for (int rr = 0; rr < 2; rr++) {
        size_t rb = ((size_t)b * PADPLANE
                     + (size_t)(y0 + 2 * ps + rr + 1) * PADW + x0 + 1) * 32;
        #pragma unroll
        for (int mt = 0; mt < 2; mt++) {
          #pragma unroll
          for (int r = 0; r < 4; r++) {
            int px = Mh * 32 + mt * 16 + q * 4 + r;
            act3[rb + (size_t)px * 32 + ntw * 16 + l15] =
                (__bf16)fmaxf(acc3[rr][mt][r], 0.f);
          }
        }
      }
      __builtin_amdgcn_s_barrier();                       // bar 4+ps
      __builtin_amdgcn_sched_barrier(0);
      sc = m6(sc + 2);
    }
  }
}

// ---------------------------------------------------------------------------
// conv4 (32->1): LDS-staged act3 reads (unchanged).
// ---------------------------------------------------------------------------
#define C4ROWB 16512   // 258 px * 32 ch * 2 B = 1032 chunks
__global__ __launch_bounds__(256, 2) void conv4_k(
    const __bf16* __restrict__ act3, const float* __restrict__ w4t,
    const float* __restrict__ b4, const float* __restrict__ sfp,
    float* __restrict__ dout)
{
  const int x = threadIdx.x, lane = threadIdx.x & 63, wave = threadIdx.x >> 6;
  const int y0 = blockIdx.x * 2, b = blockIdx.y;
  const float b4v = b4[0], sf = sfp[0];
  const __bf16* plane = act3 + (size_t)b * PADPLANE * 32;
  __shared__ __align__(16) char smem[4 * C4ROWB];

  #pragma unroll
  for (int r = 0; r < 4; r++) {
    const char* g = (const char*)(plane + (size_t)(y0 + r) * PADW * 32);
    char* lrow = smem + r * C4ROWB;
    #pragma unroll
    for (int k = 0; k < 4; k++) {
      int c = k * 256 + wave * 64 + lane;
      gl_lds(g + (size_t)swz(c) * 16, lrow + (k * 256 + wave * 64) * 16);
    }
    if (wave == 0 && lane < 8) {
      int c = 1024 + lane;
      gl_lds(g + (size_t)swz(c) * 16, lrow + 1024 * 16);
    }
  }
  asm volatile("s_waitcnt vmcnt(0)" ::: "memory");
  __builtin_amdgcn_s_barrier();

  float acc0 = b4v, acc1 = b4v;
  #pragma unroll
  for (int t = 0; t < 4; t++) {
    const char* srow = smem + t * C4ROWB;
    uint4 L[12];
    #pragma unroll
    for (int j = 0; j < 12; j++) {
      int chunk = (x + (j >> 2)) * 4 + (j & 3);
      L[j] = *(const uint4*)(srow + (size_t)swz(chunk) * 16);
    }
    #pragma unroll
    for (int j = 0; j < 12; j++) {
      const int dx = j >> 2, c0 = (j & 3) * 8;
      unsigned int uu[4] = {L[j].x, L[j].y, L[j].z, L[j].w};
      float f[8];
      #pragma unroll
      for (int k = 0; k < 4; k++) {
        f[2*k]   = __builtin_bit_cast(float, uu[k] << 16);
        f[2*k+1] = __builtin_bit_cast(float, uu[k] & 0xFFFF0000u);
      }
      if (t <= 2) {
        const float* wp = w4t + (t * 3 + dx) * 32 + c0;          // uniform
        #pragma unroll
        for (int k = 0; k < 8; k++) acc0 = fmaf(wp[k], f[k], acc0);
      }
      if (t >= 1) {
        const float* wp = w4t + ((t - 1) * 3 + dx) * 32 + c0;    // uniform
        #pragma unroll
        for (int k = 0; k < 8; k++) acc1 = fmaf(wp[k], f[k], acc1);
      }
    }
  }
  size_t p0 = ((size_t)b << 16) + (size_t)y0 * WIDTH + x;
  float vh0 = acc0 * sf, vh1 = acc1 * sf;
  dout[p0]                   = dout[524288 + p0] + vh0;          // outputs
  dout[2621440 + p0]         = vh0;                              // V_hat
  dout[p0 + WIDTH]           = dout[524288 + p0 + WIDTH] + vh1;
  dout[2621440 + p0 + WIDTH] = vh1;
}

// ---------------------------------------------------------------------------
extern "C" void kernel_launch(void* const* d_in, const int* in_sizes, int n_in,
                              void* d_out, int out_size, void* d_ws, size_t ws_size,
                              hipStream_t stream) {
  const float* inputs = (const float*)d_in[0];
  const float* H0     = (const float*)d_in[1];
  const float* C0     = (const float*)d_in[2];
  const float* c2     = (const float*)d_in[3];
  const float* sf     = (const float*)d_in[4];
  const float* w1     = (const float*)d_in[5];
  const float* b1     = (const float*)d_in[6];
  const float* w2     = (const float*)d_in[7];
  const float* b2     = (const float*)d_in[8];
  const float* w3     = (const float*)d_in[9];
  const float* b3     = (const float*)d_in[10];
  const float* w4     = (const float*)d_in[11];
  const float* b4     = (const float*)d_in[12];
  float* out = (float*)d_out;
  float* ws  = (float*)d_ws;

  float*  w1t  = ws;                               // 288 fp32
  float*  w4t  = ws + 288;                         // 288 fp32
  __bf16* B2t  = (__bf16*)(ws + 576);              // 18432 bf16
  __bf16* B3t  = (__bf16*)(ws + 9792);             // 18432 bf16
  __bf16* act1 = (__bf16*)(ws + 19008);            // 8*66564*32 bf16
  __bf16* act3 = act1 + (size_t)8 * PADPLANE * 32; // 8*66564*32 bf16

  wz_k<<<1175, 256, 0, stream>>>(w1, w2, w3, w4, w1t, B2t, B3t, w4t,
                                 act1, act3);
  prepconv1_k<<<dim3(256, 8), 256, 0, stream>>>(inputs, H0, C0, c2, sf,
                                                w1t, b1, out, act1);
  conv23_k<<<dim3(16, 4, 8), 512, 0, stream>>>(act1, B2t, b2, B3t, b3, act3);
  conv4_k<<<dim3(128, 8), 256, 0, stream>>>(act3, w4t, b4, sf, out);
}

// Round 7
// 163.308 us; speedup vs baseline: 1.0954x; 1.0071x over previous
//
#include <hip/hip_runtime.h>

#define PLANE 65536
#define WIDTH 256
#define PADW 258
#define PADPLANE 66564   // 258*258

typedef __bf16 v8bf __attribute__((ext_vector_type(8)));
typedef float  v4f  __attribute__((ext_vector_type(4)));

typedef const __attribute__((address_space(1))) unsigned int* gas_ptr;
typedef __attribute__((address_space(3))) unsigned int* las_ptr;

// async global->LDS, 16 B per lane; LDS dest = wave-uniform base + lane*16
__device__ __forceinline__ void gl_lds(const void* g, void* l) {
  __builtin_amdgcn_global_load_lds((gas_ptr)g, (las_ptr)l, 16, 0, 0);
}

// self-inverse 16B-chunk swizzle within 8-chunk groups
__device__ __forceinline__ int swz(int c) {
  return (c & ~7) | ((c & 7) ^ ((c >> 3) & 7));
}

__device__ __forceinline__ int m6(int x) { return x >= 6 ? x - 6 : x; }

__device__ __forceinline__ unsigned int pack2(float a, float b) {
  __bf16 ba = (__bf16)a, bb = (__bf16)b;
  unsigned short sa = __builtin_bit_cast(unsigned short, ba);
  unsigned short sb = __builtin_bit_cast(unsigned short, bb);
  return (unsigned int)sa | ((unsigned int)sb << 16);
}

// ---------------------------------------------------------------------------
// wz_k: fused weight-prep + padding-ring zeroing (act1 + act3 only).
// ---------------------------------------------------------------------------
#define WT_N 37440                       // 288+18432+18432+288
#define ZR_N (8 * 1028 * 32)             // 16+16 uints per ring px
__global__ __launch_bounds__(256) void wz_k(
    const float* __restrict__ w1, const float* __restrict__ w2,
    const float* __restrict__ w3, const float* __restrict__ w4,
    float* __restrict__ w1t, __bf16* __restrict__ B2t,
    __bf16* __restrict__ B3t, float* __restrict__ w4t,
    __bf16* __restrict__ a1, __bf16* __restrict__ a3)
{
  int t = blockIdx.x * 256 + threadIdx.x;
  if (t < WT_N) {
    if (t < 288) {                       // w1: [32][1][9] -> [tap][32]
      int tap = t >> 5, cout = t & 31;
      w1t[t] = w1[cout * 9 + tap];
    }
    int t2 = t - 288;
    if (t2 >= 0 && t2 < 18432) {         // 64 x 288
      int cout = t2 / 288, k = t2 % 288;
      int tap = k / 32, cin = k % 32;
      B2t[t2] = (__bf16)w2[cout * 288 + cin * 9 + tap];
    }
    int t3 = t - (288 + 18432);
    if (t3 >= 0 && t3 < 18432) {         // 32 x 576
      int cout = t3 / 576, k = t3 % 576;
      int tap = k / 64, cin = k % 64;
      B3t[t3] = (__bf16)w3[cout * 576 + cin * 9 + tap];
    }
    int t4 = t - (288 + 18432 + 18432);
    if (t4 >= 0 && t4 < 288) {           // w4: [1][32][9] -> [tap][32]
      int tap = t4 >> 5, cin = t4 & 31;
      w4t[t4] = w4[cin * 9 + tap];
    }
    return;
  }
  int idx = t - WT_N;
  if (idx >= ZR_N) return;
  unsigned int* p;
  const int R1 = 8 * 1028 * 16;
  if (idx < R1) p = (unsigned int*)a1;
  else         { p = (unsigned int*)a3; idx -= R1; }
  int ch = idx & 15;
  int pr = idx >> 4;                 // 0 .. 8*1028-1
  int b = pr / 1028, r = pr % 1028;
  int y, x;
  if      (r < 258) { y = 0;           x = r; }
  else if (r < 516) { y = 257;         x = r - 258; }
  else if (r < 772) { y = r - 516 + 1; x = 0; }
  else              { y = r - 772 + 1; x = 257; }
  p[((size_t)b * PADPLANE + y * PADW + x) * 16 + ch] = 0;
}

// ---------------------------------------------------------------------------
// prepconv1_k: fused prep + conv1 (unchanged).
// ---------------------------------------------------------------------------
__global__ __launch_bounds__(256) void prepconv1_k(
    const float* __restrict__ inputs, const float* __restrict__ H0,
    const float* __restrict__ C0, const float* __restrict__ c2p,
    const float* __restrict__ sfp, const float* __restrict__ w1t,
    const float* __restrict__ b1, float* __restrict__ dout,
    __bf16* __restrict__ act1)
{
  const int x = threadIdx.x, y = blockIdx.x, b = blockIdx.y;
  const int p = b * PLANE + y * WIDTH + x;
  const float c2 = c2p[0], sf = sfp[0], rsf = 1.0f / sf;

  float iv[3][3], hv[3][3];
  #pragma unroll
  for (int dy = 0; dy < 3; dy++) {
    int yy = y + dy - 1;
    #pragma unroll
    for (int dx = 0; dx < 3; dx++) {
      int xx = x + dx - 1;
      bool ok = (yy >= 0 && yy < 256 && xx >= 0 && xx < 256);
      int pn = p + (dy - 1) * WIDTH + (dx - 1);
      iv[dy][dx] = ok ? inputs[pn] : 0.f;
      hv[dy][dx] = ok ? H0[pn]     : 0.f;
    }
  }
  const float in = iv[1][1], h0 = hv[1][1];
  const float c0a = C0[b * 131072 + y * WIDTH + x];
  float lap = iv[0][1] + iv[2][1] + iv[1][0] + iv[1][2] - 4.f * in;
  float Hv = 2.f * in - c0a + c2 * lap;
  float V  = in - h0;
  dout[524288 + p]  = Hv;                               // H
  dout[2097152 + p] = V;                                // V
  dout[1048576 + b * 131072 + y * WIDTH + x]         = in;   // C_new[:,0]
  dout[1048576 + b * 131072 + 65536 + y * WIDTH + x] = c0a;  // C_new[:,1]

  float acc[32];
  #pragma unroll
  for (int i = 0; i < 32; i++) acc[i] = b1[i];
  #pragma unroll
  for (int tap = 0; tap < 9; tap++) {
    float v = (iv[tap / 3][tap % 3] - hv[tap / 3][tap % 3]) * rsf;
    const float* wp = w1t + tap * 32;                   // uniform
    #pragma unroll
    for (int i = 0; i < 32; i++) acc[i] = fmaf(wp[i], v, acc[i]);
  }
  unsigned int u[16];
  #pragma unroll
  for (int j = 0; j < 16; j++)
    u[j] = pack2(fmaxf(acc[2*j], 0.f), fmaxf(acc[2*j+1], 0.f));
  size_t pa = ((size_t)b * PADPLANE + (y+1) * PADW + (x+1)) * 32;
  uint4* op = reinterpret_cast<uint4*>(act1 + pa);
  #pragma unroll
  for (int j = 0; j < 4; j++)
    op[j] = make_uint4(u[4*j], u[4*j+1], u[4*j+2], u[4*j+3]);
}

// ---------------------------------------------------------------------------
// conv23_k: FUSED conv2+conv3, producer/consumer wave specialization.
//
// r6 PMC decomposition: 1104 ds_read_b128 per CU per pair-step x ~12 cyc
// = 13.2K of the 16.7K step cycles -> LDS-READ-BOUND (MfmaUtil stuck 34%).
// ROUND-7 CHANGE: producer rows are PAIRED like the consumer — producePair
// (t,t+1) reads each of the 4 underlying a1 rows once per (m,dx) and feeds
// both outputs (row t: tap dy=r; row t+1: dy=r-1). P reads/pair: 90 -> 60
// (total LDS ops/step 1104 -> 864). Per-output tap order preserved
// (dy-major, then dx, then m) -> bit-identical act2.
// ---------------------------------------------------------------------------
#define A1ROWB 4352   // 68 px * 32 ch * 2 B = 272 chunks
#define A2ROWB 8448   // 66 px * 64 ch * 2 B = 528 chunks
__global__ __launch_bounds__(512, 4) void conv23_k(
    const __bf16* __restrict__ act1, const __bf16* __restrict__ B2t,
    const float* __restrict__ b2, const __bf16* __restrict__ B3t,
    const float* __restrict__ b3, __bf16* __restrict__ act3)
{
  const int lane = threadIdx.x & 63, wave = threadIdx.x >> 6;
  const int l15 = lane & 15, q = lane >> 4;
  const int y0 = blockIdx.x * 16, xt = blockIdx.y, b = blockIdx.z;
  const int x0 = xt * 64;
  __shared__ __align__(16) char smem[6 * A2ROWB + 6 * A1ROWB + 1024];
  char* a2r = smem;                       // act2 ring (6 slots)
  char* a1r = smem + 6 * A2ROWB;          // act1 ring (6 slots; +1KB pad for
                                          //  ragged m-tile over-reads)
  const __bf16* plane = act1 + (size_t)b * PADPLANE * 32;

  if (wave < 4) {
    // ------------------------- PRODUCER (conv2) -------------------------
    auto stageA1 = [&](int k, int slot) {  // a1 rel row k = padded y0-1+k
      int a = y0 - 1 + k;
      a = a < 0 ? 0 : (a > 257 ? 257 : a);
      const char* g = (const char*)(plane + ((size_t)a * PADW + x0 - 1) * 32);
      char* lrow = a1r + slot * A1ROWB;
      const int base = wave * 68;
      gl_lds(g + (size_t)swz(base + lane) * 16, lrow + base * 16);
      if (lane < 4)
        gl_lds(g + (size_t)swz(base + 64 + lane) * 16, lrow + (base + 64) * 16);
    };

    v8bf breg2[9];                         // this wave's 16 couts
    #pragma unroll
    for (int tap = 0; tap < 9; tap++)
      breg2[tap] = *(const v8bf*)(B2t + (size_t)(wave * 16 + l15) * 288
                                      + tap * 32 + q * 8);
    const v4f bv2 = *(const v4f*)(b2 + wave * 16 + q * 4);

    auto zrow = [&](int sl) {              // zero a2 ring slot (pad row)
      char* drow = a2r + sl * A2ROWB;
      int c = threadIdx.x;                 // P-group: 0..255
      *(uint4*)(drow + (size_t)c * 16)         = make_uint4(0,0,0,0);
      *(uint4*)(drow + (size_t)(c + 256) * 16) = make_uint4(0,0,0,0);
      if (c < 16)
        *(uint4*)(drow + (size_t)(c + 512) * 16) = make_uint4(0,0,0,0);
    };

    // produce a2 rel rows t and t+1 (slots s, s+1); each a1 row read ONCE
    auto producePair = [&](int t, int s) {
      const int s1 = m6(s + 1);
      const bool z0 = (y0 + t == 0) || (y0 + t == 257);
      const bool z1 = (y0 + t + 1 == 0) || (y0 + t + 1 == 257);
      if (z0) zrow(s);
      if (z1) zrow(s1);
      if (z0 && z1) return;
      v4f acc0[5], acc1v[5];
      #pragma unroll
      for (int m = 0; m < 5; m++) { acc0[m] = bv2; acc1v[m] = bv2; }
      #pragma unroll
      for (int r = 0; r < 4; r++) {        // a1 rel row t+r (dy=r for row t)
        if (z0 && r == 0) continue;        // r0 feeds only row t
        if (z1 && r == 3) continue;        // r3 feeds only row t+1
        const char* srow = a1r + m6(s + r) * A1ROWB;
        #pragma unroll
        for (int dx = 0; dx < 3; dx++) {
          #pragma unroll
          for (int m = 0; m < 5; m++) {
            int j = m * 16 + l15 + dx;     // >67 over-reads: garbage, unused
            v8bf af = *(const v8bf*)(srow + (size_t)swz(j * 4 + q) * 16);
            if (!z0 && r <= 2)             // row t, tap (dy=r, dx)
              acc0[m] = __builtin_amdgcn_mfma_f32_16x16x32_bf16(
                  breg2[r * 3 + dx], af, acc0[m], 0, 0, 0);
            if (!z1 && r >= 1)             // row t+1, tap (dy=r-1, dx)
              acc1v[m] = __builtin_amdgcn_mfma_f32_16x16x32_bf16(
                  breg2[(r - 1) * 3 + dx], af, acc1v[m], 0, 0, 0);
          }
        }
      }
      const int c = wave * 2 + (q >> 1), boff = (q & 1) * 8;
      #pragma unroll
      for (int rr = 0; rr < 2; rr++) {
        if (rr == 0 && z0) continue;
        if (rr == 1 && z1) continue;
        char* drow = a2r + (rr ? s1 : s) * A2ROWB;
        v4f* A = rr ? acc1v : acc0;
        #pragma unroll
        for (int m = 0; m < 5; m++) {
          int px = m * 16 + l15;
          bool w = (m < 4) || (l15 < 2);               // px <= 65
          if (x0 == 0   && px == 0)  w = false;        // x-halo -> zeroed
          if (x0 == 192 && px == 65) w = false;
          if (w) {
            unsigned int lo = pack2(fmaxf(A[m][0], 0.f), fmaxf(A[m][1], 0.f));
            unsigned int hi = pack2(fmaxf(A[m][2], 0.f), fmaxf(A[m][3], 0.f));
            *(uint2*)(drow + (size_t)swz(px * 8 + c) * 16 + boff)
                = make_uint2(lo, hi);
          }
        }
        if (x0 == 0 && threadIdx.x < 8)            // zero px slot 0 (x=-1)
          *(uint4*)(drow + (size_t)swz(threadIdx.x) * 16) = make_uint4(0,0,0,0);
        if (x0 == 192 && threadIdx.x < 8)          // zero px slot 65 (x=256)
          *(uint4*)(drow + (size_t)swz(520 + threadIdx.x) * 16) = make_uint4(0,0,0,0);
      }
    };

    // prologue: a1 rows 0..5; produce a2 rows 0..3; a1 rows 6,7
    #pragma unroll
    for (int k = 0; k < 6; k++) stageA1(k, k);
    asm volatile("s_waitcnt vmcnt(0)" ::: "memory");
    __builtin_amdgcn_s_barrier();                         // bar 1
    __builtin_amdgcn_sched_barrier(0);
    producePair(0, 0); producePair(2, 2);
    asm volatile("s_waitcnt lgkmcnt(0)" ::: "memory");
    __builtin_amdgcn_s_barrier();                         // bar 2
    __builtin_amdgcn_sched_barrier(0);
    stageA1(6, 0); stageA1(7, 1);
    asm volatile("s_waitcnt vmcnt(0)" ::: "memory");
    __builtin_amdgcn_s_barrier();                         // bar 3
    __builtin_amdgcn_sched_barrier(0);

    int sb = 2;                                           // (2ps+2)%6
    for (int ps = 0; ps < 8; ps++) {
      // stage a1 rows 2ps+8,9 (clamped; land in just-freed slots)
      int r0 = 2 * ps + 8, r1 = 2 * ps + 9;
      stageA1(r0 > 19 ? 19 : r0, sb);
      stageA1(r1 > 19 ? 19 : r1, m6(sb + 1));
      // produce a2 rows 2ps+4,5 (a1 rows 2ps+4..2ps+7 staged+drained)
      if (2 * ps + 4 <= 17) producePair(2 * ps + 4, m6(sb + 2));
      // own-wave drains BEFORE the shared barrier (cross-wave visibility)
      asm volatile("s_waitcnt vmcnt(0) lgkmcnt(0)" ::: "memory");
      __builtin_amdgcn_s_barrier();                       // bar 4+ps
      __builtin_amdgcn_sched_barrier(0);
      sb = m6(sb + 2);
    }
  } else {
    // ------------------------- CONSUMER (conv3) -------------------------
    const int cw = wave - 4;
    const int Mh = cw >> 1, ntw = cw & 1;
    v8bf breg3[9][2];                          // tap, kb
    #pragma unroll
    for (int tap = 0; tap < 9; tap++)
      #pragma unroll
      for (int kb = 0; kb < 2; kb++)
        breg3[tap][kb] = *(const v8bf*)(B3t + (size_t)(ntw * 16 + l15) * 576
                                            + tap * 64 + kb * 32 + q * 8);
    const float bv3 = b3[ntw * 16 + l15];

    __builtin_amdgcn_s_barrier();                         // bar 1
    __builtin_amdgcn_s_barrier();                         // bar 2
    __builtin_amdgcn_s_barrier();                         // bar 3

    int sc = 0;                                           // (2ps)%6
    for (int ps = 0; ps < 8; ps++) {
      v4f acc3[2][2];                             // [rr][mt]
      #pragma unroll
      for (int rr = 0; rr < 2; rr++)
        #pragma unroll
        for (int mt = 0; mt < 2; mt++)
          acc3[rr][mt] = (v4f){bv3, bv3, bv3, bv3};

      __builtin_amdgcn_s_setprio(1);
      #pragma unroll
      for (int t = 0; t < 4; t++) {
        const char* srow = a2r + m6(sc + t) * A2ROWB;
        #pragma unroll
        for (int dx = 0; dx < 3; dx++) {
          #pragma unroll
          for (int kb = 0; kb < 2; kb++) {
            v8bf af[2];
            #pragma unroll
            for (int mt = 0; mt < 2; mt++) {
              int P = Mh * 32 + mt * 16 + l15 + dx;   // 0..65
              af[mt] = *(const v8bf*)(srow + (size_t)swz(P * 8 + kb * 4 + q) * 16);
            }
            #pragma unroll
            for (int mt = 0; mt < 2; mt++) {
              if (t <= 2)
                acc3[0][mt] = __builtin_amdgcn_mfma_f32_16x16x32_bf16(
                    af[mt], breg3[t * 3 + dx][kb], acc3[0][mt], 0, 0, 0);
              if (t >= 1)
                acc3[1][mt] = __builtin_amdgcn_mfma_f32_16x16x32_bf16(
                    af[mt], breg3[(t - 1) * 3 + dx][kb], acc3[1][mt], 0, 0, 0);
            }
          }
        }
      }
      __builtin_amdgcn_s_setprio(0);

      #pragma unroll
      for (int rr = 0; rr < 2; rr++) {
        size_t rb = ((size_t)b * PADPLANE
                     + (size_t)(y0 + 2 * ps + rr + 1) * PADW + x0 + 1) * 32;
        #pragma unroll
        for (int mt = 0; mt < 2; mt++) {
          #pragma unroll
          for (int r = 0; r < 4; r++) {
            int px = Mh * 32 + mt * 16 + q * 4 + r;
            act3[rb + (size_t)px * 32 + ntw * 16 + l15] =
                (__bf16)fmaxf(acc3[rr][mt][r], 0.f);
          }
        }
      }
      __builtin_amdgcn_s_barrier();                       // bar 4+ps
      __builtin_amdgcn_sched_barrier(0);
      sc = m6(sc + 2);
    }
  }
}

// ---------------------------------------------------------------------------
// conv4 (32->1): LDS-staged act3 reads (unchanged).
// ---------------------------------------------------------------------------
#define C4ROWB 16512   // 258 px * 32 ch * 2 B = 1032 chunks
__global__ __launch_bounds__(256, 2) void conv4_k(
    const __bf16* __restrict__ act3, const float* __restrict__ w4t,
    const float* __restrict__ b4, const float* __restrict__ sfp,
    float* __restrict__ dout)
{
  const int x = threadIdx.x, lane = threadIdx.x & 63, wave = threadIdx.x >> 6;
  const int y0 = blockIdx.x * 2, b = blockIdx.y;
  const float b4v = b4[0], sf = sfp[0];
  const __bf16* plane = act3 + (size_t)b * PADPLANE * 32;
  __shared__ __align__(16) char smem[4 * C4ROWB];

  #pragma unroll
  for (int r = 0; r < 4; r++) {
    const char* g = (const char*)(plane + (size_t)(y0 + r) * PADW * 32);
    char* lrow = smem + r * C4ROWB;
    #pragma unroll
    for (int k = 0; k < 4; k++) {
      int c = k * 256 + wave * 64 + lane;
      gl_lds(g + (size_t)swz(c) * 16, lrow + (k * 256 + wave * 64) * 16);
    }
    if (wave == 0 && lane < 8) {
      int c = 1024 + lane;
      gl_lds(g + (size_t)swz(c) * 16, lrow + 1024 * 16);
    }
  }
  asm volatile("s_waitcnt vmcnt(0)" ::: "memory");
  __builtin_amdgcn_s_barrier();

  float acc0 = b4v, acc1 = b4v;
  #pragma unroll
  for (int t = 0; t < 4; t++) {
    const char* srow = smem + t * C4ROWB;
    uint4 L[12];
    #pragma unroll
    for (int j = 0; j < 12; j++) {
      int chunk = (x + (j >> 2)) * 4 + (j & 3);
      L[j] = *(const uint4*)(srow + (size_t)swz(chunk) * 16);
    }
    #pragma unroll
    for (int j = 0; j < 12; j++) {
      const int dx = j >> 2, c0 = (j & 3) * 8;
      unsigned int uu[4] = {L[j].x, L[j].y, L[j].z, L[j].w};
      float f[8];
      #pragma unroll
      for (int k = 0; k < 4; k++) {
        f[2*k]   = __builtin_bit_cast(float, uu[k] << 16);
        f[2*k+1] = __builtin_bit_cast(float, uu[k] & 0xFFFF0000u);
      }
      if (t <= 2) {
        const float* wp = w4t + (t * 3 + dx) * 32 + c0;          // uniform
        #pragma unroll
        for (int k = 0; k < 8; k++) acc0 = fmaf(wp[k], f[k], acc0);
      }
      if (t >= 1) {
        const float* wp = w4t + ((t - 1) * 3 + dx) * 32 + c0;    // uniform
        #pragma unroll
        for (int k = 0; k < 8; k++) acc1 = fmaf(wp[k], f[k], acc1);
      }
    }
  }
  size_t p0 = ((size_t)b << 16) + (size_t)y0 * WIDTH + x;
  float vh0 = acc0 * sf, vh1 = acc1 * sf;
  dout[p0]                   = dout[524288 + p0] + vh0;          // outputs
  dout[2621440 + p0]         = vh0;                              // V_hat
  dout[p0 + WIDTH]           = dout[524288 + p0 + WIDTH] + vh1;
  dout[2621440 + p0 + WIDTH] = vh1;
}

// ---------------------------------------------------------------------------
extern "C" void kernel_launch(void* const* d_in, const int* in_sizes, int n_in,
                              void* d_out, int out_size, void* d_ws, size_t ws_size,
                              hipStream_t stream) {
  const float* inputs = (const float*)d_in[0];
  const float* H0     = (const float*)d_in[1];
  const float* C0     = (const float*)d_in[2];
  const float* c2     = (const float*)d_in[3];
  const float* sf     = (const float*)d_in[4];
  const float* w1     = (const float*)d_in[5];
  const float* b1     = (const float*)d_in[6];
  const float* w2     = (const float*)d_in[7];
  const float* b2     = (const float*)d_in[8];
  const float* w3     = (const float*)d_in[9];
  const float* b3     = (const float*)d_in[10];
  const float* w4     = (const float*)d_in[11];
  const float* b4     = (const float*)d_in[12];
  float* out = (float*)d_out;
  float* ws  = (float*)d_ws;

  float*  w1t  = ws;                               // 288 fp32
  float*  w4t  = ws + 288;                         // 288 fp32
  __bf16* B2t  = (__bf16*)(ws + 576);              // 18432 bf16
  __bf16* B3t  = (__bf16*)(ws + 9792);             // 18432 bf16
  __bf16* act1 = (__bf16*)(ws + 19008);            // 8*66564*32 bf16
  __bf16* act3 = act1 + (size_t)8 * PADPLANE * 32; // 8*66564*32 bf16

  wz_k<<<1175, 256, 0, stream>>>(w1, w2, w3, w4, w1t, B2t, B3t, w4t,
                                 act1, act3);
  prepconv1_k<<<dim3(256, 8), 256, 0, stream>>>(inputs, H0, C0, c2, sf,
                                                w1t, b1, out, act1);
  conv23_k<<<dim3(16, 4, 8), 512, 0, stream>>>(act1, B2t, b2, B3t, b3, act3);
  conv4_k<<<dim3(128, 8), 256, 0, stream>>>(act3, w4t, b4, sf, out);
}